// Round 13
// baseline (40.731 us; speedup 1.0000x reference)
//
#include <hip/hip_runtime.h>

// Fixed sizes
#define G_    32
#define O_    16
#define OUTD  128
#define DS_   64      // scalar half / SDIM
#define VC    48      // V*3
#define M_    2048    // rows per graph
#define ROWS  128     // rows per chunk
#define CPG   16      // chunks per graph
#define XP    136     // xT / cT pitch in bf16 elems (rows 16B-aligned: 272B)
#define XPD   68      // pitch in dwords
#define WVP   72      // wv_s pitch in bf16
#define XNP   72      // xN pitch in bf16 (row-major scalar half)
#define YLP   132     // y_lds pitch in f32

typedef __attribute__((ext_vector_type(8))) short short8;
typedef __attribute__((ext_vector_type(4))) float f32x4;
typedef unsigned long long u64_t;

__device__ __forceinline__ unsigned short f2bf(float f) {
  unsigned u = __float_as_uint(f);
  return (unsigned short)((u + 0x7FFFu + ((u >> 16) & 1u)) >> 16);
}
__device__ __forceinline__ float bf2f(short v) {
  return __uint_as_float(((unsigned)(unsigned short)v) << 16);
}

// 8B coherent I/O: relaxed agent-scope u64 atomics (R6/R7-validated).
__device__ __forceinline__ void st8f(float* p, float a, float b) {
  union { float f[2]; u64_t u; } x; x.f[0] = a; x.f[1] = b;
  __hip_atomic_store((u64_t*)p, x.u, __ATOMIC_RELAXED, __HIP_MEMORY_SCOPE_AGENT);
}
__device__ __forceinline__ void ld8f(const float* p, float& a, float& b) {
  union { float f[2]; u64_t u; } x;
  x.u = __hip_atomic_load((const u64_t*)p, __ATOMIC_RELAXED, __HIP_MEMORY_SCOPE_AGENT);
  a = x.f[0]; b = x.f[1];
}

// Per-graph barrier (16 blocks/graph), fence-free (R6/R7/R11/R12-validated).
__device__ __forceinline__ void graph_barrier(unsigned* cnt, unsigned target) {
  asm volatile("s_waitcnt vmcnt(0)" ::: "memory");
  __syncthreads();
  if (threadIdx.x == 0) {
    __hip_atomic_fetch_add(cnt, 1u, __ATOMIC_RELAXED, __HIP_MEMORY_SCOPE_AGENT);
    unsigned guard = 0;
    while (__hip_atomic_load(cnt, __ATOMIC_RELAXED, __HIP_MEMORY_SCOPE_AGENT) < target) {
      __builtin_amdgcn_s_sleep(1);
      if (++guard > (1u << 20)) break;
    }
  }
  __syncthreads();
}

// ---------------------------------------------------------------------------
// R13 = R12 + per-phase latency cuts:
//  - ysum via global f32 atomics in stage (R10-validated volume) -> B0 reads
//    a single pre-reduced value instead of a 16-deep coherent-load chain.
//  - B-phase y-reduce spread over all 512 threads (depth 16 -> 2) with LDS
//    partials in psum[64][33], which ALIASES y_lds (barrier-separated uses;
//    64*33 = 2112 = 16*YLP exactly) -> LDS unchanged, 2 blocks/CU kept.
// ---------------------------------------------------------------------------
__global__ __launch_bounds__(512) void caps_mega4(
    const float* __restrict__ x, const float* __restrict__ xv,
    const float* __restrict__ Ws, const float* __restrict__ Wv,
    const float* __restrict__ bias, short* __restrict__ wvacc_bf,
    float* __restrict__ y_part, float* __restrict__ routed_part,
    float* __restrict__ ysum, float* __restrict__ caps,
    float* __restrict__ vecs, unsigned* __restrict__ bar)
{
  const int b = blockIdx.x, g = b >> 4, chunk = b & 15;
  const int t = threadIdx.x, h = t >> 8, tt = t & 255;
  const int lane = t & 63, w = t >> 6;   // 8 waves

  __shared__ short xT[128 * XP];        // 34816 B, persistent
  __shared__ short xN[128 * XNP];       // 18432 B, persistent (scalar half)
  __shared__ short cT[O_ * XP];         // 4352 B
  __shared__ short wv_s[O_ * WVP];      // 2304 B
  __shared__ float scratch[16 * YLP];   // 8448 B: A=y_lds  B=psum[64][33]
  __shared__ float cp_s[16][17];        // 1088 B
  __shared__ float xv_s[16 * VC];       // 3072 B
  __shared__ float yB[128];             // 512 B
  __shared__ float ps[2][128];          // 1024 B
  __shared__ float vB[64];              // 256 B
  __shared__ float pn_s[2];             // 8 B
  __shared__ float wv_acc_s[64];        // 256 B
  // total ~74.75 KB -> 2 blocks/CU

  unsigned* cnt = bar + g * 64;

  // ========== phase 0: stage x -> xT (+ xN for k<64) ========================
  {
    const float* xg = x + (size_t)b * (ROWS * OUTD);
    const int rg = tt >> 2, qc = tt & 3;
    const float* r0 = xg + (size_t)(2 * rg) * OUTD + qc * 32 + h * 16;
    const float* r1 = r0 + OUTD;
    const float4* r0q = (const float4*)r0;
    const float4* r1q = (const float4*)r1;
    float4 a0 = r0q[0], a1 = r0q[1], a2 = r0q[2], a3 = r0q[3];
    float4 b0 = r1q[0], b1 = r1q[1], b2 = r1q[2], b3 = r1q[3];
    unsigned* xTd = (unsigned*)xT;
    const int cb = qc * 32 + h * 16;
#define STAGE4(S, A, B)                                                        \
    xTd[(cb + S*4 + 0) * XPD + rg] = (unsigned)f2bf(A.x) | ((unsigned)f2bf(B.x) << 16); \
    xTd[(cb + S*4 + 1) * XPD + rg] = (unsigned)f2bf(A.y) | ((unsigned)f2bf(B.y) << 16); \
    xTd[(cb + S*4 + 2) * XPD + rg] = (unsigned)f2bf(A.z) | ((unsigned)f2bf(B.z) << 16); \
    xTd[(cb + S*4 + 3) * XPD + rg] = (unsigned)f2bf(A.w) | ((unsigned)f2bf(B.w) << 16);
    STAGE4(0, a0, b0) STAGE4(1, a1, b1) STAGE4(2, a2, b2) STAGE4(3, a3, b3)
#undef STAGE4
    // row-major copy (scalar half only, cols < 64): 4x short8 stores
    if (qc < 2) {
      short8 p0, p1, q0, q1;
      p0[0]=f2bf(a0.x); p0[1]=f2bf(a0.y); p0[2]=f2bf(a0.z); p0[3]=f2bf(a0.w);
      p0[4]=f2bf(a1.x); p0[5]=f2bf(a1.y); p0[6]=f2bf(a1.z); p0[7]=f2bf(a1.w);
      p1[0]=f2bf(a2.x); p1[1]=f2bf(a2.y); p1[2]=f2bf(a2.z); p1[3]=f2bf(a2.w);
      p1[4]=f2bf(a3.x); p1[5]=f2bf(a3.y); p1[6]=f2bf(a3.z); p1[7]=f2bf(a3.w);
      q0[0]=f2bf(b0.x); q0[1]=f2bf(b0.y); q0[2]=f2bf(b0.z); q0[3]=f2bf(b0.w);
      q0[4]=f2bf(b1.x); q0[5]=f2bf(b1.y); q0[6]=f2bf(b1.z); q0[7]=f2bf(b1.w);
      q1[0]=f2bf(b2.x); q1[1]=f2bf(b2.y); q1[2]=f2bf(b2.z); q1[3]=f2bf(b2.w);
      q1[4]=f2bf(b3.x); q1[5]=f2bf(b3.y); q1[6]=f2bf(b3.z); q1[7]=f2bf(b3.w);
      *(short8*)&xN[(2 * rg + 0) * XNP + cb]     = p0;
      *(short8*)&xN[(2 * rg + 0) * XNP + cb + 8] = p1;
      *(short8*)&xN[(2 * rg + 1) * XNP + cb]     = q0;
      *(short8*)&xN[(2 * rg + 1) * XNP + cb + 8] = q1;
    }
  }
  {
    const float* xvg = xv + (size_t)(g * 256 + chunk * 16) * VC;
    for (int i = t; i < 16 * VC; i += 512) xv_s[i] = xvg[i];
  }
  __syncthreads();
  if (h == 0) {   // colsums -> global f32 atomic accumulate (R10-validated)
    const int k = tt >> 1, half = tt & 1;
    float s = 0.f;
#pragma unroll
    for (int j = 0; j < 8; ++j) {
      short8 v = *(const short8*)&xT[k * XP + half * 64 + j * 8];
#pragma unroll
      for (int e = 0; e < 8; ++e) s += bf2f(v[e]);
    }
    s += __shfl_xor(s, 1);
    if (half == 0) unsafeAtomicAdd(&ysum[(size_t)g * 128 + k], s);
  }
  graph_barrier(cnt, 16);

  // ---- role macros ---------------------------------------------------------
#define A_ROLE(LASTF)                                                          \
  {                                                                            \
    if (t < 256) {                                                             \
      u64_t v4 = __hip_atomic_load(                                            \
          (const u64_t*)&wvacc_bf[(size_t)g * 1024 + t * 4],                   \
          __ATOMIC_RELAXED, __HIP_MEMORY_SCOPE_AGENT);                         \
      const int o = t >> 4, k = (t * 4) & 63;                                  \
      wv_s[o * WVP + k + 0] = (short)(v4 & 0xFFFF);                            \
      wv_s[o * WVP + k + 1] = (short)((v4 >> 16) & 0xFFFF);                    \
      wv_s[o * WVP + k + 2] = (short)((v4 >> 32) & 0xFFFF);                    \
      wv_s[o * WVP + k + 3] = (short)((v4 >> 48) & 0xFFFF);                    \
    }                                                                          \
    __syncthreads();                                                           \
    /* GEMM1 + softmax: wave w owns m-tile nt = w; B-op from xN (b128) */      \
    { const int mrow = lane & 15, gq = lane >> 4;                              \
      const int nt = w;                                                        \
      const int mcol = nt * 16 + mrow;                                         \
      f32x4 acc = {0.f, 0.f, 0.f, 0.f};                                        \
      _Pragma("unroll")                                                        \
      for (int ks = 0; ks < 2; ++ks) {                                         \
        short8 af = *(const short8*)&wv_s[mrow * WVP + ks * 32 + gq * 8];      \
        short8 bfr = *(const short8*)&xN[mcol * XNP + ks * 32 + gq * 8];       \
        acc = __builtin_amdgcn_mfma_f32_16x16x32_bf16(af, bfr, acc, 0, 0, 0);  \
      }                                                                        \
      float mx = fmaxf(fmaxf(acc[0], acc[1]), fmaxf(acc[2], acc[3]));          \
      mx = fmaxf(mx, __shfl_xor(mx, 16));                                      \
      mx = fmaxf(mx, __shfl_xor(mx, 32));                                      \
      float e0 = __expf(acc[0] - mx), e1 = __expf(acc[1] - mx);                \
      float e2 = __expf(acc[2] - mx), e3 = __expf(acc[3] - mx);                \
      float sm = e0 + e1 + e2 + e3;                                            \
      sm += __shfl_xor(sm, 16);                                                \
      sm += __shfl_xor(sm, 32);                                                \
      float inv = 1.f / sm;                                                    \
      float c0 = e0 * inv, c1 = e1 * inv, c2 = e2 * inv, c3 = e3 * inv;        \
      cT[(gq * 4 + 0) * XP + mcol] = (short)f2bf(c0);                          \
      cT[(gq * 4 + 1) * XP + mcol] = (short)f2bf(c1);                          \
      cT[(gq * 4 + 2) * XP + mcol] = (short)f2bf(c2);                          \
      cT[(gq * 4 + 3) * XP + mcol] = (short)f2bf(c3);                          \
      if (LASTF) {                                                             \
        float cf[4] = {c0, c1, c2, c3};                                        \
        _Pragma("unroll")                                                      \
        for (int r = 0; r < 4; ++r) {                                          \
          float v = cf[r];                                                     \
          v += __shfl_xor(v, 1); v += __shfl_xor(v, 2); v += __shfl_xor(v, 4); \
          if ((lane & 7) == 0)                                                 \
            cp_s[nt * 2 + ((lane >> 3) & 1)][gq * 4 + r] = v;                  \
        }                                                                      \
      } }                                                                      \
    __syncthreads();                                                           \
    /* GEMM2: wave w owns k-tile w; y_lds = scratch */                         \
    { const int oc = lane & 15, gq = lane >> 4;                                \
      f32x4 y0 = {0.f,0.f,0.f,0.f};                                            \
      _Pragma("unroll")                                                        \
      for (int ks = 0; ks < 4; ++ks) {                                         \
        short8 bfv = *(const short8*)&cT[oc * XP + ks * 32 + gq * 8];          \
        short8 av = *(const short8*)&xT[(w * 16 + oc) * XP + ks * 32 + gq * 8];\
        y0 = __builtin_amdgcn_mfma_f32_16x16x32_bf16(av, bfv, y0, 0, 0, 0);    \
      }                                                                        \
      _Pragma("unroll")                                                        \
      for (int r = 0; r < 4; ++r)                                              \
        scratch[oc * YLP + w * 16 + gq * 4 + r] = y0[r]; }                     \
    __syncthreads();                                                           \
    { float* yp = y_part + (size_t)b * 2048;                                   \
      const int oo = t >> 5, kk = (t * 4) & 127;                               \
      const float* sp = &scratch[oo * YLP + kk];                               \
      st8f(&yp[t * 4], sp[0], sp[1]);                                          \
      st8f(&yp[t * 4 + 2], sp[2], sp[3]); }                                    \
    if (LASTF) {                                                               \
      if (t < 384) {                                                           \
        float* rp = routed_part + (size_t)b * 768;                             \
        const int idx0 = 2 * t;                                                \
        const int o = idx0 / VC, j = idx0 - o * VC;                            \
        float a0 = 0.f, a1 = 0.f;                                              \
        _Pragma("unroll")                                                      \
        for (int n = 0; n < 16; ++n) {                                         \
          a0 += cp_s[n][o] * xv_s[n * VC + j];                                 \
          a1 += cp_s[n][o] * xv_s[n * VC + j + 1];                             \
        }                                                                      \
        st8f(&rp[idx0], a0, a1);                                               \
      } }                                                                      \
  }

#define B_ROLE(FIRSTF, LASTF)                                                  \
  {                                                                            \
    const int o = chunk;                                                       \
    if (FIRSTF) {                                                              \
      if (t < 64) {                                                            \
        float a, bb;                                                           \
        ld8f(&ysum[(size_t)g * 128 + 2 * t], a, bb);                           \
        yB[2*t] = a * 0.0625f; yB[2*t+1] = bb * 0.0625f;                       \
      }                                                                        \
    } else {                                                                   \
      /* spread y-reduce: (ch, kpair) over 512 thr, depth 2; psum=scratch */   \
      { const int ch = t & 15, kp0 = t >> 4;    /* kp0 in 0..31 */             \
        const float* yp = y_part + (size_t)g * CPG * 2048 + ch * 2048 + o * 128;\
        float a, bb, c, d;                                                     \
        ld8f(&yp[2 * kp0], a, bb);                                             \
        ld8f(&yp[2 * (kp0 + 32)], c, d);                                       \
        scratch[kp0 * 33 + ch * 2]        = a;                                 \
        scratch[kp0 * 33 + ch * 2 + 1]    = bb;                                \
        scratch[(kp0 + 32) * 33 + ch * 2]     = c;                             \
        scratch[(kp0 + 32) * 33 + ch * 2 + 1] = d; }                           \
      __syncthreads();                                                         \
      if (t < 64) {                                                            \
        float s0 = 0.f, s1 = 0.f;                                              \
        _Pragma("unroll")                                                      \
        for (int ch = 0; ch < CPG; ++ch) {                                     \
          s0 += scratch[t * 33 + ch * 2];                                      \
          s1 += scratch[t * 33 + ch * 2 + 1];                                  \
        }                                                                      \
        yB[2*t] = s0; yB[2*t+1] = s1;                                          \
      }                                                                        \
    }                                                                          \
    __syncthreads();                                                           \
    if (t < 256) {   /* s-GEMM, k-split 2-way (R10/R11/R12-validated) */       \
      const int kh = t >> 7, d = t & 127;                                      \
      const float* W = (d < 64) ? (Ws + (size_t)o * 4096 + d)                  \
                                : (Wv + (size_t)o * 4096 + (d - 64));          \
      const int ybase = (d < 64) ? 0 : 64;                                     \
      float a0 = 0.f, a1 = 0.f;                                                \
      _Pragma("unroll")                                                        \
      for (int k = 0; k < 32; k += 2) {                                        \
        const int kl = kh * 32 + k;                                            \
        a0 += yB[ybase + kl] * W[(size_t)kl * 64];                             \
        a1 += yB[ybase + kl + 1] * W[(size_t)(kl + 1) * 64];                   \
      }                                                                        \
      ps[kh][d] = a0 + a1;                                                     \
    }                                                                          \
    __syncthreads();                                                           \
    float sv = 0.f;                                                            \
    if (t < 128) {                                                             \
      sv = ps[0][t] + ps[1][t] + bias[o * OUTD + t];                           \
      float pn = sv * sv;                                                      \
      _Pragma("unroll")                                                        \
      for (int m = 1; m < 64; m <<= 1) pn += __shfl_xor(pn, m);                \
      if ((t & 63) == 0) pn_s[t >> 6] = pn;                                    \
    }                                                                          \
    __syncthreads();                                                           \
    if (t < 128) {                                                             \
      float sn = pn_s[0] + pn_s[1];                                            \
      float f = sn / ((1.f + sn) * (sqrtf(sn) + 1e-8f));                       \
      float v = f * sv;                                                        \
      if (t < 64) vB[t] = v;                                                   \
      if (LASTF) caps[((size_t)g * O_ + o) * OUTD + t] = v;                    \
    }                                                                          \
    __syncthreads();                                                           \
    if (!(LASTF)) {                                                            \
      if (t < 128) {  /* wvacc update, 2-way s-split (validated) */            \
        const int k = t >> 1, half = t & 1;                                    \
        const float* Wr = Ws + ((size_t)o * 64 + k) * 64 + half * 32;          \
        float acc = 0.f;                                                       \
        _Pragma("unroll")                                                      \
        for (int ss = 0; ss < 32; ss += 4) {                                   \
          float4 wq = *(const float4*)(Wr + ss);                               \
          float4 vq = *(const float4*)&vB[half * 32 + ss];                     \
          acc += wq.x*vq.x + wq.y*vq.y + wq.z*vq.z + wq.w*vq.w;                \
        }                                                                      \
        acc += __shfl_xor(acc, 1);                                             \
        if (half == 0)                                                         \
          wv_acc_s[k] = ((FIRSTF) ? 0.f : wv_acc_s[k]) + acc;                  \
      }                                                                        \
      __syncthreads();                                                         \
      if (t < 16) {   /* pack bf16 x4 -> u64 coherent store (validated) */     \
        const int k = t * 4;                                                   \
        u64_t v4 =  (u64_t)(unsigned short)f2bf(wv_acc_s[k + 0])               \
                 | ((u64_t)(unsigned short)f2bf(wv_acc_s[k + 1]) << 16)        \
                 | ((u64_t)(unsigned short)f2bf(wv_acc_s[k + 2]) << 32)        \
                 | ((u64_t)(unsigned short)f2bf(wv_acc_s[k + 3]) << 48);       \
        __hip_atomic_store(                                                    \
            (u64_t*)&wvacc_bf[(size_t)g * 1024 + o * 64 + k],                  \
            v4, __ATOMIC_RELAXED, __HIP_MEMORY_SCOPE_AGENT);                   \
      }                                                                        \
    } else {                                                                   \
      if (t < 24) {                                                            \
        const int idx = o * VC + 2 * t;                                        \
        const float* rp = routed_part + (size_t)g * CPG * 768 + idx;           \
        float s0 = 0.f, s1 = 0.f;                                              \
        _Pragma("unroll")                                                      \
        for (int ch = 0; ch < CPG; ++ch) {                                     \
          float a, bb; ld8f(&rp[ch * 768], a, bb);                             \
          s0 += a; s1 += bb;                                                   \
        }                                                                      \
        vecs[(size_t)g * 768 + idx] = s0;                                      \
        vecs[(size_t)g * 768 + idx + 1] = s1;                                  \
      }                                                                        \
    }                                                                          \
  }

  // ================= routing iterations =================
  B_ROLE(1, 0)                 // it0 B: v0 from atomic colsums, wvacc '='
  graph_barrier(cnt, 32);
  A_ROLE(0)                    // it1 A
  graph_barrier(cnt, 48);
  B_ROLE(0, 0)                 // it1 B: wvacc '+='
  graph_barrier(cnt, 64);
  A_ROLE(1)                    // it2 A: + cp + routed partials
  graph_barrier(cnt, 80);
  B_ROLE(0, 1)                 // it2 B: caps + vecs

#undef A_ROLE
#undef B_ROLE
}

// ---------------------------------------------------------------------------
extern "C" void kernel_launch(void* const* d_in, const int* in_sizes, int n_in,
                              void* d_out, int out_size, void* d_ws, size_t ws_size,
                              hipStream_t stream)
{
  const float* x    = (const float*)d_in[0];
  const float* xv   = (const float*)d_in[1];
  const float* Ws   = (const float*)d_in[2];
  const float* Wv   = (const float*)d_in[3];
  const float* bias = (const float*)d_in[4];

  float* out  = (float*)d_out;
  float* caps = out;                           // (32,16,128)
  float* vecs = out + (size_t)G_ * O_ * OUTD;  // (32,16,16,3)

  // ws layout: bar (2048 u32, 8KB) | ysum (4096 f, 16KB) | y_part 1048576 f
  //            | routed 393216 f | wvacc_bf 32768 bf16
  float* ws          = (float*)d_ws;
  unsigned* bar      = (unsigned*)ws;
  float* ysum        = ws + 2048;
  float* y_part      = ysum + 4096;
  float* routed_part = y_part + (size_t)G_ * CPG * 2048;
  short* wvacc_bf    = (short*)(routed_part + (size_t)G_ * CPG * 768);

  // zero barrier counters + ysum atomic accumulator (24 KB)
  hipMemsetAsync((void*)bar, 0, 24576, stream);
  caps_mega4<<<dim3(G_ * CPG), dim3(512), 0, stream>>>(
      x, xv, Ws, Wv, bias, wvacc_bf, y_part, routed_part, ysum,
      caps, vecs, bar);
}

// Round 14
// 40.621 us; speedup vs baseline: 1.0027x; 1.0027x over previous
//
#include <hip/hip_runtime.h>

// Fixed sizes
#define G_    32
#define O_    16
#define OUTD  128
#define DS_   64      // scalar half / SDIM
#define VC    48      // V*3
#define M_    2048    // rows per graph
#define ROWS  128     // rows per chunk
#define CPG   16      // chunks per graph
#define XP    136     // xT / cT pitch in bf16 elems (rows 16B-aligned: 272B)
#define XPD   68      // pitch in dwords
#define WVP   72      // wv_s pitch in bf16
#define XNP   72      // xN pitch in bf16 (row-major scalar half)
#define YLP   132     // y_lds pitch in f32

typedef __attribute__((ext_vector_type(8))) short short8;
typedef __attribute__((ext_vector_type(4))) float f32x4;
typedef unsigned long long u64_t;

__device__ __forceinline__ unsigned short f2bf(float f) {
  unsigned u = __float_as_uint(f);
  return (unsigned short)((u + 0x7FFFu + ((u >> 16) & 1u)) >> 16);
}
__device__ __forceinline__ float bf2f(short v) {
  return __uint_as_float(((unsigned)(unsigned short)v) << 16);
}

// 8B coherent I/O: relaxed agent-scope u64 atomics (R6/R7-validated).
__device__ __forceinline__ void st8f(float* p, float a, float b) {
  union { float f[2]; u64_t u; } x; x.f[0] = a; x.f[1] = b;
  __hip_atomic_store((u64_t*)p, x.u, __ATOMIC_RELAXED, __HIP_MEMORY_SCOPE_AGENT);
}
__device__ __forceinline__ void ld8f(const float* p, float& a, float& b) {
  union { float f[2]; u64_t u; } x;
  x.u = __hip_atomic_load((const u64_t*)p, __ATOMIC_RELAXED, __HIP_MEMORY_SCOPE_AGENT);
  a = x.f[0]; b = x.f[1];
}

// Per-graph barrier (16 blocks/graph), fence-free (R6/R7/R11/R12-validated).
__device__ __forceinline__ void graph_barrier(unsigned* cnt, unsigned target) {
  asm volatile("s_waitcnt vmcnt(0)" ::: "memory");
  __syncthreads();
  if (threadIdx.x == 0) {
    __hip_atomic_fetch_add(cnt, 1u, __ATOMIC_RELAXED, __HIP_MEMORY_SCOPE_AGENT);
    unsigned guard = 0;
    while (__hip_atomic_load(cnt, __ATOMIC_RELAXED, __HIP_MEMORY_SCOPE_AGENT) < target) {
      __builtin_amdgcn_s_sleep(1);
      if (++guard > (1u << 20)) break;
    }
  }
  __syncthreads();
}

// ---------------------------------------------------------------------------
// R14 = R12 (best passing, 39.7us) + XCD-grouping block swizzle:
//   xcd = b&7 (HW round-robin b -> XCD b%8), g = xcd*4 + ((b>>3)&3),
//   chunk = b>>5.  All 16 blocks of a graph land on ONE XCD, making the
//   graph's barrier counter + y_part exchange XCD-local instead of
//   worst-case cross-die. Pure permutation: math/buffers identical to R12.
// ---------------------------------------------------------------------------
__global__ __launch_bounds__(512) void caps_mega5(
    const float* __restrict__ x, const float* __restrict__ xv,
    const float* __restrict__ Ws, const float* __restrict__ Wv,
    const float* __restrict__ bias, short* __restrict__ wvacc_bf,
    float* __restrict__ y_part, float* __restrict__ routed_part,
    float* __restrict__ ysum_part, float* __restrict__ caps,
    float* __restrict__ vecs, unsigned* __restrict__ bar)
{
  const int b = blockIdx.x;
  const int xcd = b & 7, mid = (b >> 3) & 3;
  const int g = xcd * 4 + mid, chunk = b >> 5;   // all chunks of g: same XCD
  const int blk_lin = g * CPG + chunk;
  const int t = threadIdx.x, h = t >> 8, tt = t & 255;
  const int lane = t & 63, w = t >> 6;   // 8 waves

  __shared__ short xT[128 * XP];        // 34816 B, persistent
  __shared__ short xN[128 * XNP];       // 18432 B, persistent (scalar half)
  __shared__ short cT[O_ * XP];         // 4352 B
  __shared__ short wv_s[O_ * WVP];      // 2304 B
  __shared__ float y_lds[16 * YLP];     // 8448 B
  __shared__ float cp_s[16][17];        // 1088 B
  __shared__ float xv_s[16 * VC];       // 3072 B
  __shared__ float yB[128];             // 512 B
  __shared__ float ps[2][128];          // 1024 B
  __shared__ float vB[64];              // 256 B
  __shared__ float pn_s[2];             // 8 B
  __shared__ float wv_acc_s[64];        // 256 B
  // total ~74.75 KB -> 2 blocks/CU

  unsigned* cnt = bar + g * 64;

  // ========== phase 0: stage x -> xT (+ xN for k<64) ========================
  {
    const float* xg = x + (size_t)blk_lin * (ROWS * OUTD);
    const int rg = tt >> 2, qc = tt & 3;
    const float* r0 = xg + (size_t)(2 * rg) * OUTD + qc * 32 + h * 16;
    const float* r1 = r0 + OUTD;
    const float4* r0q = (const float4*)r0;
    const float4* r1q = (const float4*)r1;
    float4 a0 = r0q[0], a1 = r0q[1], a2 = r0q[2], a3 = r0q[3];
    float4 b0 = r1q[0], b1 = r1q[1], b2 = r1q[2], b3 = r1q[3];
    unsigned* xTd = (unsigned*)xT;
    const int cb = qc * 32 + h * 16;
#define STAGE4(S, A, B)                                                        \
    xTd[(cb + S*4 + 0) * XPD + rg] = (unsigned)f2bf(A.x) | ((unsigned)f2bf(B.x) << 16); \
    xTd[(cb + S*4 + 1) * XPD + rg] = (unsigned)f2bf(A.y) | ((unsigned)f2bf(B.y) << 16); \
    xTd[(cb + S*4 + 2) * XPD + rg] = (unsigned)f2bf(A.z) | ((unsigned)f2bf(B.z) << 16); \
    xTd[(cb + S*4 + 3) * XPD + rg] = (unsigned)f2bf(A.w) | ((unsigned)f2bf(B.w) << 16);
    STAGE4(0, a0, b0) STAGE4(1, a1, b1) STAGE4(2, a2, b2) STAGE4(3, a3, b3)
#undef STAGE4
    // row-major copy (scalar half only, cols < 64): 4x short8 stores
    if (qc < 2) {
      short8 p0, p1, q0, q1;
      p0[0]=f2bf(a0.x); p0[1]=f2bf(a0.y); p0[2]=f2bf(a0.z); p0[3]=f2bf(a0.w);
      p0[4]=f2bf(a1.x); p0[5]=f2bf(a1.y); p0[6]=f2bf(a1.z); p0[7]=f2bf(a1.w);
      p1[0]=f2bf(a2.x); p1[1]=f2bf(a2.y); p1[2]=f2bf(a2.z); p1[3]=f2bf(a2.w);
      p1[4]=f2bf(a3.x); p1[5]=f2bf(a3.y); p1[6]=f2bf(a3.z); p1[7]=f2bf(a3.w);
      q0[0]=f2bf(b0.x); q0[1]=f2bf(b0.y); q0[2]=f2bf(b0.z); q0[3]=f2bf(b0.w);
      q0[4]=f2bf(b1.x); q0[5]=f2bf(b1.y); q0[6]=f2bf(b1.z); q0[7]=f2bf(b1.w);
      q1[0]=f2bf(b2.x); q1[1]=f2bf(b2.y); q1[2]=f2bf(b2.z); q1[3]=f2bf(b2.w);
      q1[4]=f2bf(b3.x); q1[5]=f2bf(b3.y); q1[6]=f2bf(b3.z); q1[7]=f2bf(b3.w);
      *(short8*)&xN[(2 * rg + 0) * XNP + cb]     = p0;
      *(short8*)&xN[(2 * rg + 0) * XNP + cb + 8] = p1;
      *(short8*)&xN[(2 * rg + 1) * XNP + cb]     = q0;
      *(short8*)&xN[(2 * rg + 1) * XNP + cb + 8] = q1;
    }
  }
  {
    const float* xvg = xv + (size_t)(g * 256 + chunk * 16) * VC;
    for (int i = t; i < 16 * VC; i += 512) xv_s[i] = xvg[i];
  }
  __syncthreads();
  if (h == 0) {   // colsums (R7/R12-validated pattern)
    const int k = tt >> 1, half = tt & 1;
    float s = 0.f;
#pragma unroll
    for (int j = 0; j < 8; ++j) {
      short8 v = *(const short8*)&xT[k * XP + half * 64 + j * 8];
#pragma unroll
      for (int e = 0; e < 8; ++e) s += bf2f(v[e]);
    }
    s += __shfl_xor(s, 1);
    float s1 = __shfl_xor(s, 2);
    if ((tt & 3) == 0) st8f(&ysum_part[(size_t)blk_lin * 128 + k], s, s1);
  }
  graph_barrier(cnt, 16);

  // ---- role macros ---------------------------------------------------------
#define A_ROLE(LASTF)                                                          \
  {                                                                            \
    if (t < 256) {                                                             \
      u64_t v4 = __hip_atomic_load(                                            \
          (const u64_t*)&wvacc_bf[(size_t)g * 1024 + t * 4],                   \
          __ATOMIC_RELAXED, __HIP_MEMORY_SCOPE_AGENT);                         \
      const int o = t >> 4, k = (t * 4) & 63;                                  \
      wv_s[o * WVP + k + 0] = (short)(v4 & 0xFFFF);                            \
      wv_s[o * WVP + k + 1] = (short)((v4 >> 16) & 0xFFFF);                    \
      wv_s[o * WVP + k + 2] = (short)((v4 >> 32) & 0xFFFF);                    \
      wv_s[o * WVP + k + 3] = (short)((v4 >> 48) & 0xFFFF);                    \
    }                                                                          \
    __syncthreads();                                                           \
    /* GEMM1 + softmax: wave w owns m-tile nt = w; B-op from xN (b128) */      \
    { const int mrow = lane & 15, gq = lane >> 4;                              \
      const int nt = w;                                                        \
      const int mcol = nt * 16 + mrow;                                         \
      f32x4 acc = {0.f, 0.f, 0.f, 0.f};                                        \
      _Pragma("unroll")                                                        \
      for (int ks = 0; ks < 2; ++ks) {                                         \
        short8 af = *(const short8*)&wv_s[mrow * WVP + ks * 32 + gq * 8];      \
        short8 bfr = *(const short8*)&xN[mcol * XNP + ks * 32 + gq * 8];       \
        acc = __builtin_amdgcn_mfma_f32_16x16x32_bf16(af, bfr, acc, 0, 0, 0);  \
      }                                                                        \
      float mx = fmaxf(fmaxf(acc[0], acc[1]), fmaxf(acc[2], acc[3]));          \
      mx = fmaxf(mx, __shfl_xor(mx, 16));                                      \
      mx = fmaxf(mx, __shfl_xor(mx, 32));                                      \
      float e0 = __expf(acc[0] - mx), e1 = __expf(acc[1] - mx);                \
      float e2 = __expf(acc[2] - mx), e3 = __expf(acc[3] - mx);                \
      float sm = e0 + e1 + e2 + e3;                                            \
      sm += __shfl_xor(sm, 16);                                                \
      sm += __shfl_xor(sm, 32);                                                \
      float inv = 1.f / sm;                                                    \
      float c0 = e0 * inv, c1 = e1 * inv, c2 = e2 * inv, c3 = e3 * inv;        \
      cT[(gq * 4 + 0) * XP + mcol] = (short)f2bf(c0);                          \
      cT[(gq * 4 + 1) * XP + mcol] = (short)f2bf(c1);                          \
      cT[(gq * 4 + 2) * XP + mcol] = (short)f2bf(c2);                          \
      cT[(gq * 4 + 3) * XP + mcol] = (short)f2bf(c3);                          \
      if (LASTF) {                                                             \
        float cf[4] = {c0, c1, c2, c3};                                        \
        _Pragma("unroll")                                                      \
        for (int r = 0; r < 4; ++r) {                                          \
          float v = cf[r];                                                     \
          v += __shfl_xor(v, 1); v += __shfl_xor(v, 2); v += __shfl_xor(v, 4); \
          if ((lane & 7) == 0)                                                 \
            cp_s[nt * 2 + ((lane >> 3) & 1)][gq * 4 + r] = v;                  \
        }                                                                      \
      } }                                                                      \
    __syncthreads();                                                           \
    /* GEMM2: wave w owns k-tile w */                                          \
    { const int oc = lane & 15, gq = lane >> 4;                                \
      f32x4 y0 = {0.f,0.f,0.f,0.f};                                            \
      _Pragma("unroll")                                                        \
      for (int ks = 0; ks < 4; ++ks) {                                         \
        short8 bfv = *(const short8*)&cT[oc * XP + ks * 32 + gq * 8];          \
        short8 av = *(const short8*)&xT[(w * 16 + oc) * XP + ks * 32 + gq * 8];\
        y0 = __builtin_amdgcn_mfma_f32_16x16x32_bf16(av, bfv, y0, 0, 0, 0);    \
      }                                                                        \
      _Pragma("unroll")                                                        \
      for (int r = 0; r < 4; ++r)                                              \
        y_lds[oc * YLP + w * 16 + gq * 4 + r] = y0[r]; }                       \
    __syncthreads();                                                           \
    { float* yp = y_part + (size_t)blk_lin * 2048;                             \
      const int oo = t >> 5, kk = (t * 4) & 127;                               \
      const float* sp = &y_lds[oo * YLP + kk];                                 \
      st8f(&yp[t * 4], sp[0], sp[1]);                                          \
      st8f(&yp[t * 4 + 2], sp[2], sp[3]); }                                    \
    if (LASTF) {                                                               \
      if (t < 384) {                                                           \
        float* rp = routed_part + (size_t)blk_lin * 768;                       \
        const int idx0 = 2 * t;                                                \
        const int o = idx0 / VC, j = idx0 - o * VC;                            \
        float a0 = 0.f, a1 = 0.f;                                              \
        _Pragma("unroll")                                                      \
        for (int n = 0; n < 16; ++n) {                                         \
          a0 += cp_s[n][o] * xv_s[n * VC + j];                                 \
          a1 += cp_s[n][o] * xv_s[n * VC + j + 1];                             \
        }                                                                      \
        st8f(&rp[idx0], a0, a1);                                               \
      } }                                                                      \
  }

#define B_ROLE(FIRSTF, LASTF)                                                  \
  {                                                                            \
    const int o = chunk;                                                       \
    if (t < 64) {                                                              \
      float s0 = 0.f, s1 = 0.f;                                                \
      if (FIRSTF) {                                                            \
        _Pragma("unroll")                                                      \
        for (int ch = 0; ch < CPG; ++ch) {                                     \
          float a, bb;                                                         \
          ld8f(&ysum_part[(size_t)(g * CPG + ch) * 128 + 2 * t], a, bb);       \
          s0 += a; s1 += bb;                                                   \
        }                                                                      \
        s0 *= 0.0625f; s1 *= 0.0625f;                                          \
      } else {                                                                 \
        const float* yp = y_part + (size_t)g * CPG * 2048 + o * 128 + 2 * t;   \
        _Pragma("unroll")                                                      \
        for (int ch = 0; ch < CPG; ++ch) {                                     \
          float a, bb; ld8f(&yp[ch * 2048], a, bb);                            \
          s0 += a; s1 += bb;                                                   \
        }                                                                      \
      }                                                                        \
      yB[2*t] = s0; yB[2*t+1] = s1;                                            \
    }                                                                          \
    __syncthreads();                                                           \
    if (t < 256) {   /* s-GEMM, k-split 2-way (R10/R11/R12-validated) */       \
      const int kh = t >> 7, d = t & 127;                                      \
      const float* W = (d < 64) ? (Ws + (size_t)o * 4096 + d)                  \
                                : (Wv + (size_t)o * 4096 + (d - 64));          \
      const int ybase = (d < 64) ? 0 : 64;                                     \
      float a0 = 0.f, a1 = 0.f;                                                \
      _Pragma("unroll")                                                        \
      for (int k = 0; k < 32; k += 2) {                                        \
        const int kl = kh * 32 + k;                                            \
        a0 += yB[ybase + kl] * W[(size_t)kl * 64];                             \
        a1 += yB[ybase + kl + 1] * W[(size_t)(kl + 1) * 64];                   \
      }                                                                        \
      ps[kh][d] = a0 + a1;                                                     \
    }                                                                          \
    __syncthreads();                                                           \
    float sv = 0.f;                                                            \
    if (t < 128) {                                                             \
      sv = ps[0][t] + ps[1][t] + bias[o * OUTD + t];                           \
      float pn = sv * sv;                                                      \
      _Pragma("unroll")                                                        \
      for (int m = 1; m < 64; m <<= 1) pn += __shfl_xor(pn, m);                \
      if ((t & 63) == 0) pn_s[t >> 6] = pn;                                    \
    }                                                                          \
    __syncthreads();                                                           \
    if (t < 128) {                                                             \
      float sn = pn_s[0] + pn_s[1];                                            \
      float f = sn / ((1.f + sn) * (sqrtf(sn) + 1e-8f));                       \
      float v = f * sv;                                                        \
      if (t < 64) vB[t] = v;                                                   \
      if (LASTF) caps[((size_t)g * O_ + o) * OUTD + t] = v;                    \
    }                                                                          \
    __syncthreads();                                                           \
    if (!(LASTF)) {                                                            \
      if (t < 128) {  /* wvacc update, 2-way s-split (validated) */            \
        const int k = t >> 1, half = t & 1;                                    \
        const float* Wr = Ws + ((size_t)o * 64 + k) * 64 + half * 32;          \
        float acc = 0.f;                                                       \
        _Pragma("unroll")                                                      \
        for (int ss = 0; ss < 32; ss += 4) {                                   \
          float4 wq = *(const float4*)(Wr + ss);                               \
          float4 vq = *(const float4*)&vB[half * 32 + ss];                     \
          acc += wq.x*vq.x + wq.y*vq.y + wq.z*vq.z + wq.w*vq.w;                \
        }                                                                      \
        acc += __shfl_xor(acc, 1);                                             \
        if (half == 0)                                                         \
          wv_acc_s[k] = ((FIRSTF) ? 0.f : wv_acc_s[k]) + acc;                  \
      }                                                                        \
      __syncthreads();                                                         \
      if (t < 16) {   /* pack bf16 x4 -> u64 coherent store (validated) */     \
        const int k = t * 4;                                                   \
        u64_t v4 =  (u64_t)(unsigned short)f2bf(wv_acc_s[k + 0])               \
                 | ((u64_t)(unsigned short)f2bf(wv_acc_s[k + 1]) << 16)        \
                 | ((u64_t)(unsigned short)f2bf(wv_acc_s[k + 2]) << 32)        \
                 | ((u64_t)(unsigned short)f2bf(wv_acc_s[k + 3]) << 48);       \
        __hip_atomic_store(                                                    \
            (u64_t*)&wvacc_bf[(size_t)g * 1024 + o * 64 + k],                  \
            v4, __ATOMIC_RELAXED, __HIP_MEMORY_SCOPE_AGENT);                   \
      }                                                                        \
    } else {                                                                   \
      if (t < 24) {                                                            \
        const int idx = o * VC + 2 * t;                                        \
        const float* rp = routed_part + (size_t)g * CPG * 768 + idx;           \
        float s0 = 0.f, s1 = 0.f;                                              \
        _Pragma("unroll")                                                      \
        for (int ch = 0; ch < CPG; ++ch) {                                     \
          float a, bb; ld8f(&rp[ch * 768], a, bb);                             \
          s0 += a; s1 += bb;                                                   \
        }                                                                      \
        vecs[(size_t)g * 768 + idx] = s0;                                      \
        vecs[(size_t)g * 768 + idx + 1] = s1;                                  \
      }                                                                        \
    }                                                                          \
  }

  // ================= routing iterations =================
  B_ROLE(1, 0)                 // it0 B: v0 from colsums, wvacc '='
  graph_barrier(cnt, 32);
  A_ROLE(0)                    // it1 A
  graph_barrier(cnt, 48);
  B_ROLE(0, 0)                 // it1 B: wvacc '+='
  graph_barrier(cnt, 64);
  A_ROLE(1)                    // it2 A: + cp + routed partials
  graph_barrier(cnt, 80);
  B_ROLE(0, 1)                 // it2 B: caps + vecs

#undef A_ROLE
#undef B_ROLE
}

// ---------------------------------------------------------------------------
extern "C" void kernel_launch(void* const* d_in, const int* in_sizes, int n_in,
                              void* d_out, int out_size, void* d_ws, size_t ws_size,
                              hipStream_t stream)
{
  const float* x    = (const float*)d_in[0];
  const float* xv   = (const float*)d_in[1];
  const float* Ws   = (const float*)d_in[2];
  const float* Wv   = (const float*)d_in[3];
  const float* bias = (const float*)d_in[4];

  float* out  = (float*)d_out;
  float* caps = out;                           // (32,16,128)
  float* vecs = out + (size_t)G_ * O_ * OUTD;  // (32,16,16,3)

  // ws layout: bar (2048 u32) | ysum_part 65536 f | y_part 1048576 f
  //            | routed 393216 f | wvacc_bf 32768 bf16
  float* ws          = (float*)d_ws;
  unsigned* bar      = (unsigned*)ws;
  float* ysum_part   = ws + 4096;
  float* y_part      = ysum_part + (size_t)G_ * CPG * 128;
  float* routed_part = y_part + (size_t)G_ * CPG * 2048;
  short* wvacc_bf    = (short*)(routed_part + (size_t)G_ * CPG * 768);

  hipMemsetAsync((void*)bar, 0, (size_t)G_ * 64 * sizeof(unsigned), stream);
  caps_mega5<<<dim3(G_ * CPG), dim3(512), 0, stream>>>(
      x, xv, Ws, Wv, bias, wvacc_bf, y_part, routed_part, ysum_part,
      caps, vecs, bar);
}

// Round 15
// 39.432 us; speedup vs baseline: 1.0329x; 1.0301x over previous
//
#include <hip/hip_runtime.h>

// Fixed sizes
#define G_    32
#define O_    16
#define OUTD  128
#define DS_   64      // scalar half / SDIM
#define VC    48      // V*3
#define M_    2048    // rows per graph
#define ROWS  128     // rows per chunk
#define CPG   16      // chunks per graph
#define XP    136     // xT / cT pitch in bf16 elems (rows 16B-aligned: 272B)
#define XPD   68      // pitch in dwords
#define WVP   72      // wv_s pitch in bf16
#define XNP   72      // xN pitch in bf16 (row-major scalar half)
#define YLP   132     // y_lds pitch in f32

typedef __attribute__((ext_vector_type(8))) short short8;
typedef __attribute__((ext_vector_type(4))) float f32x4;
typedef unsigned long long u64_t;

__device__ __forceinline__ unsigned short f2bf(float f) {
  unsigned u = __float_as_uint(f);
  return (unsigned short)((u + 0x7FFFu + ((u >> 16) & 1u)) >> 16);
}
__device__ __forceinline__ float bf2f(short v) {
  return __uint_as_float(((unsigned)(unsigned short)v) << 16);
}
// HW packed f32x2 -> bf16x2 (RNE, same as f2bf; m240-verified mnemonic)
__device__ __forceinline__ unsigned cvtpk(float lo, float hi) {
  unsigned r;
  asm("v_cvt_pk_bf16_f32 %0, %1, %2" : "=v"(r) : "v"(lo), "v"(hi));
  return r;
}

// 8B coherent I/O: relaxed agent-scope u64 atomics (R6/R7-validated).
__device__ __forceinline__ void st8f(float* p, float a, float b) {
  union { float f[2]; u64_t u; } x; x.f[0] = a; x.f[1] = b;
  __hip_atomic_store((u64_t*)p, x.u, __ATOMIC_RELAXED, __HIP_MEMORY_SCOPE_AGENT);
}
__device__ __forceinline__ void ld8f(const float* p, float& a, float& b) {
  union { float f[2]; u64_t u; } x;
  x.u = __hip_atomic_load((const u64_t*)p, __ATOMIC_RELAXED, __HIP_MEMORY_SCOPE_AGENT);
  a = x.f[0]; b = x.f[1];
}

// Per-graph barrier (16 blocks/graph), fence-free (R6/R7/R11/R12-validated).
__device__ __forceinline__ void graph_barrier(unsigned* cnt, unsigned target) {
  asm volatile("s_waitcnt vmcnt(0)" ::: "memory");
  __syncthreads();
  if (threadIdx.x == 0) {
    __hip_atomic_fetch_add(cnt, 1u, __ATOMIC_RELAXED, __HIP_MEMORY_SCOPE_AGENT);
    unsigned guard = 0;
    while (__hip_atomic_load(cnt, __ATOMIC_RELAXED, __HIP_MEMORY_SCOPE_AGENT) < target) {
      __builtin_amdgcn_s_sleep(1);
      if (++guard > (1u << 20)) break;
    }
  }
  __syncthreads();
}

// ---------------------------------------------------------------------------
// R15 = R12 (best passing, 39.7us) + stage rewrite:
//  - thread map (rg = t&63 m-pair, c16 = t>>6 col-16-block): transpose dword
//    stores become 2-way bank access (free) instead of 4-way (measured 885K
//    SQ_LDS_BANK_CONFLICT: qc-groups 32 k-rows apart always shared banks).
//  - f2bf bit-twiddle (~10 VALU/pair) -> v_cvt_pk_bf16_f32 (1 VALU/pair).
//  All phases after stage are byte-identical to R12.
// ---------------------------------------------------------------------------
__global__ __launch_bounds__(512) void caps_mega6(
    const float* __restrict__ x, const float* __restrict__ xv,
    const float* __restrict__ Ws, const float* __restrict__ Wv,
    const float* __restrict__ bias, short* __restrict__ wvacc_bf,
    float* __restrict__ y_part, float* __restrict__ routed_part,
    float* __restrict__ ysum_part, float* __restrict__ caps,
    float* __restrict__ vecs, unsigned* __restrict__ bar)
{
  const int b = blockIdx.x, g = b >> 4, chunk = b & 15;
  const int t = threadIdx.x, h = t >> 8, tt = t & 255;
  const int lane = t & 63, w = t >> 6;   // 8 waves

  __shared__ short xT[128 * XP];        // 34816 B, persistent
  __shared__ short xN[128 * XNP];       // 18432 B, persistent (scalar half)
  __shared__ short cT[O_ * XP];         // 4352 B
  __shared__ short wv_s[O_ * WVP];      // 2304 B
  __shared__ float y_lds[16 * YLP];     // 8448 B
  __shared__ float cp_s[16][17];        // 1088 B
  __shared__ float xv_s[16 * VC];       // 3072 B
  __shared__ float yB[128];             // 512 B
  __shared__ float ps[2][128];          // 1024 B
  __shared__ float vB[64];              // 256 B
  __shared__ float pn_s[2];             // 8 B
  __shared__ float wv_acc_s[64];        // 256 B
  // total ~74.75 KB -> 2 blocks/CU

  unsigned* cnt = bar + g * 64;

  // ========== phase 0: stage x -> xT (+ xN for k<64), conflict-free =========
  {
    const float* xg = x + (size_t)b * (ROWS * OUTD);
    const int rg = t & 63, c16 = t >> 6;      // m-pair 0..63, col-block 0..7
    const float* r0 = xg + (size_t)(2 * rg) * OUTD + c16 * 16;
    const float* r1 = r0 + OUTD;
    const float4* r0q = (const float4*)r0;
    const float4* r1q = (const float4*)r1;
    float4 a0 = r0q[0], a1 = r0q[1], a2 = r0q[2], a3 = r0q[3];
    float4 b0 = r1q[0], b1 = r1q[1], b2 = r1q[2], b3 = r1q[3];
    // transposed: dword k -> (bf16(row 2rg), bf16(row 2rg+1)); per-wave k is
    // uniform (c16 const across wave) -> banks (k*4+rg)&31, rg 0..63 = 2-way
    unsigned* xTd = (unsigned*)xT;
    const int kb = c16 * 16;
    xTd[(kb +  0) * XPD + rg] = cvtpk(a0.x, b0.x);
    xTd[(kb +  1) * XPD + rg] = cvtpk(a0.y, b0.y);
    xTd[(kb +  2) * XPD + rg] = cvtpk(a0.z, b0.z);
    xTd[(kb +  3) * XPD + rg] = cvtpk(a0.w, b0.w);
    xTd[(kb +  4) * XPD + rg] = cvtpk(a1.x, b1.x);
    xTd[(kb +  5) * XPD + rg] = cvtpk(a1.y, b1.y);
    xTd[(kb +  6) * XPD + rg] = cvtpk(a1.z, b1.z);
    xTd[(kb +  7) * XPD + rg] = cvtpk(a1.w, b1.w);
    xTd[(kb +  8) * XPD + rg] = cvtpk(a2.x, b2.x);
    xTd[(kb +  9) * XPD + rg] = cvtpk(a2.y, b2.y);
    xTd[(kb + 10) * XPD + rg] = cvtpk(a2.z, b2.z);
    xTd[(kb + 11) * XPD + rg] = cvtpk(a2.w, b2.w);
    xTd[(kb + 12) * XPD + rg] = cvtpk(a3.x, b3.x);
    xTd[(kb + 13) * XPD + rg] = cvtpk(a3.y, b3.y);
    xTd[(kb + 14) * XPD + rg] = cvtpk(a3.z, b3.z);
    xTd[(kb + 15) * XPD + rg] = cvtpk(a3.w, b3.w);
    // row-major xN (scalar half, cols < 64): b128 per 8-col half-row
    if (c16 < 4) {
      union { unsigned u[4]; short8 s; } p;
      p.u[0] = cvtpk(a0.x, a0.y); p.u[1] = cvtpk(a0.z, a0.w);
      p.u[2] = cvtpk(a1.x, a1.y); p.u[3] = cvtpk(a1.z, a1.w);
      *(short8*)&xN[(2 * rg) * XNP + kb] = p.s;
      p.u[0] = cvtpk(a2.x, a2.y); p.u[1] = cvtpk(a2.z, a2.w);
      p.u[2] = cvtpk(a3.x, a3.y); p.u[3] = cvtpk(a3.z, a3.w);
      *(short8*)&xN[(2 * rg) * XNP + kb + 8] = p.s;
      p.u[0] = cvtpk(b0.x, b0.y); p.u[1] = cvtpk(b0.z, b0.w);
      p.u[2] = cvtpk(b1.x, b1.y); p.u[3] = cvtpk(b1.z, b1.w);
      *(short8*)&xN[(2 * rg + 1) * XNP + kb] = p.s;
      p.u[0] = cvtpk(b2.x, b2.y); p.u[1] = cvtpk(b2.z, b2.w);
      p.u[2] = cvtpk(b3.x, b3.y); p.u[3] = cvtpk(b3.z, b3.w);
      *(short8*)&xN[(2 * rg + 1) * XNP + kb + 8] = p.s;
    }
  }
  {
    const float* xvg = xv + (size_t)(g * 256 + chunk * 16) * VC;
    for (int i = t; i < 16 * VC; i += 512) xv_s[i] = xvg[i];
  }
  __syncthreads();
  if (h == 0) {   // colsums (R7/R12-validated pattern)
    const int k = tt >> 1, half = tt & 1;
    float s = 0.f;
#pragma unroll
    for (int j = 0; j < 8; ++j) {
      short8 v = *(const short8*)&xT[k * XP + half * 64 + j * 8];
#pragma unroll
      for (int e = 0; e < 8; ++e) s += bf2f(v[e]);
    }
    s += __shfl_xor(s, 1);
    float s1 = __shfl_xor(s, 2);
    if ((tt & 3) == 0) st8f(&ysum_part[(size_t)b * 128 + k], s, s1);
  }
  graph_barrier(cnt, 16);

  // ---- role macros ---------------------------------------------------------
#define A_ROLE(LASTF)                                                          \
  {                                                                            \
    if (t < 256) {                                                             \
      u64_t v4 = __hip_atomic_load(                                            \
          (const u64_t*)&wvacc_bf[(size_t)g * 1024 + t * 4],                   \
          __ATOMIC_RELAXED, __HIP_MEMORY_SCOPE_AGENT);                         \
      const int o = t >> 4, k = (t * 4) & 63;                                  \
      wv_s[o * WVP + k + 0] = (short)(v4 & 0xFFFF);                            \
      wv_s[o * WVP + k + 1] = (short)((v4 >> 16) & 0xFFFF);                    \
      wv_s[o * WVP + k + 2] = (short)((v4 >> 32) & 0xFFFF);                    \
      wv_s[o * WVP + k + 3] = (short)((v4 >> 48) & 0xFFFF);                    \
    }                                                                          \
    __syncthreads();                                                           \
    /* GEMM1 + softmax: wave w owns m-tile nt = w; B-op from xN (b128) */      \
    { const int mrow = lane & 15, gq = lane >> 4;                              \
      const int nt = w;                                                        \
      const int mcol = nt * 16 + mrow;                                         \
      f32x4 acc = {0.f, 0.f, 0.f, 0.f};                                        \
      _Pragma("unroll")                                                        \
      for (int ks = 0; ks < 2; ++ks) {                                         \
        short8 af = *(const short8*)&wv_s[mrow * WVP + ks * 32 + gq * 8];      \
        short8 bfr = *(const short8*)&xN[mcol * XNP + ks * 32 + gq * 8];       \
        acc = __builtin_amdgcn_mfma_f32_16x16x32_bf16(af, bfr, acc, 0, 0, 0);  \
      }                                                                        \
      float mx = fmaxf(fmaxf(acc[0], acc[1]), fmaxf(acc[2], acc[3]));          \
      mx = fmaxf(mx, __shfl_xor(mx, 16));                                      \
      mx = fmaxf(mx, __shfl_xor(mx, 32));                                      \
      float e0 = __expf(acc[0] - mx), e1 = __expf(acc[1] - mx);                \
      float e2 = __expf(acc[2] - mx), e3 = __expf(acc[3] - mx);                \
      float sm = e0 + e1 + e2 + e3;                                            \
      sm += __shfl_xor(sm, 16);                                                \
      sm += __shfl_xor(sm, 32);                                                \
      float inv = 1.f / sm;                                                    \
      float c0 = e0 * inv, c1 = e1 * inv, c2 = e2 * inv, c3 = e3 * inv;        \
      cT[(gq * 4 + 0) * XP + mcol] = (short)f2bf(c0);                          \
      cT[(gq * 4 + 1) * XP + mcol] = (short)f2bf(c1);                          \
      cT[(gq * 4 + 2) * XP + mcol] = (short)f2bf(c2);                          \
      cT[(gq * 4 + 3) * XP + mcol] = (short)f2bf(c3);                          \
      if (LASTF) {                                                             \
        float cf[4] = {c0, c1, c2, c3};                                        \
        _Pragma("unroll")                                                      \
        for (int r = 0; r < 4; ++r) {                                          \
          float v = cf[r];                                                     \
          v += __shfl_xor(v, 1); v += __shfl_xor(v, 2); v += __shfl_xor(v, 4); \
          if ((lane & 7) == 0)                                                 \
            cp_s[nt * 2 + ((lane >> 3) & 1)][gq * 4 + r] = v;                  \
        }                                                                      \
      } }                                                                      \
    __syncthreads();                                                           \
    /* GEMM2: wave w owns k-tile w */                                          \
    { const int oc = lane & 15, gq = lane >> 4;                                \
      f32x4 y0 = {0.f,0.f,0.f,0.f};                                            \
      _Pragma("unroll")                                                        \
      for (int ks = 0; ks < 4; ++ks) {                                         \
        short8 bfv = *(const short8*)&cT[oc * XP + ks * 32 + gq * 8];          \
        short8 av = *(const short8*)&xT[(w * 16 + oc) * XP + ks * 32 + gq * 8];\
        y0 = __builtin_amdgcn_mfma_f32_16x16x32_bf16(av, bfv, y0, 0, 0, 0);    \
      }                                                                        \
      _Pragma("unroll")                                                        \
      for (int r = 0; r < 4; ++r)                                              \
        y_lds[oc * YLP + w * 16 + gq * 4 + r] = y0[r]; }                       \
    __syncthreads();                                                           \
    { float* yp = y_part + (size_t)b * 2048;                                   \
      const int oo = t >> 5, kk = (t * 4) & 127;                               \
      const float* sp = &y_lds[oo * YLP + kk];                                 \
      st8f(&yp[t * 4], sp[0], sp[1]);                                          \
      st8f(&yp[t * 4 + 2], sp[2], sp[3]); }                                    \
    if (LASTF) {                                                               \
      if (t < 384) {                                                           \
        float* rp = routed_part + (size_t)b * 768;                             \
        const int idx0 = 2 * t;                                                \
        const int o = idx0 / VC, j = idx0 - o * VC;                            \
        float a0 = 0.f, a1 = 0.f;                                              \
        _Pragma("unroll")                                                      \
        for (int n = 0; n < 16; ++n) {                                         \
          a0 += cp_s[n][o] * xv_s[n * VC + j];                                 \
          a1 += cp_s[n][o] * xv_s[n * VC + j + 1];                             \
        }                                                                      \
        st8f(&rp[idx0], a0, a1);                                               \
      } }                                                                      \
  }

#define B_ROLE(FIRSTF, LASTF)                                                  \
  {                                                                            \
    const int o = chunk;                                                       \
    if (t < 64) {                                                              \
      float s0 = 0.f, s1 = 0.f;                                                \
      if (FIRSTF) {                                                            \
        _Pragma("unroll")                                                      \
        for (int ch = 0; ch < CPG; ++ch) {                                     \
          float a, bb;                                                         \
          ld8f(&ysum_part[(size_t)(g * CPG + ch) * 128 + 2 * t], a, bb);       \
          s0 += a; s1 += bb;                                                   \
        }                                                                      \
        s0 *= 0.0625f; s1 *= 0.0625f;                                          \
      } else {                                                                 \
        const float* yp = y_part + (size_t)g * CPG * 2048 + o * 128 + 2 * t;   \
        _Pragma("unroll")                                                      \
        for (int ch = 0; ch < CPG; ++ch) {                                     \
          float a, bb; ld8f(&yp[ch * 2048], a, bb);                            \
          s0 += a; s1 += bb;                                                   \
        }                                                                      \
      }                                                                        \
      yB[2*t] = s0; yB[2*t+1] = s1;                                            \
    }                                                                          \
    __syncthreads();                                                           \
    if (t < 256) {   /* s-GEMM, k-split 2-way (R10/R11/R12-validated) */       \
      const int kh = t >> 7, d = t & 127;                                      \
      const float* W = (d < 64) ? (Ws + (size_t)o * 4096 + d)                  \
                                : (Wv + (size_t)o * 4096 + (d - 64));          \
      const int ybase = (d < 64) ? 0 : 64;                                     \
      float a0 = 0.f, a1 = 0.f;                                                \
      _Pragma("unroll")                                                        \
      for (int k = 0; k < 32; k += 2) {                                        \
        const int kl = kh * 32 + k;                                            \
        a0 += yB[ybase + kl] * W[(size_t)kl * 64];                             \
        a1 += yB[ybase + kl + 1] * W[(size_t)(kl + 1) * 64];                   \
      }                                                                        \
      ps[kh][d] = a0 + a1;                                                     \
    }                                                                          \
    __syncthreads();                                                           \
    float sv = 0.f;                                                            \
    if (t < 128) {                                                             \
      sv = ps[0][t] + ps[1][t] + bias[o * OUTD + t];                           \
      float pn = sv * sv;                                                      \
      _Pragma("unroll")                                                        \
      for (int m = 1; m < 64; m <<= 1) pn += __shfl_xor(pn, m);                \
      if ((t & 63) == 0) pn_s[t >> 6] = pn;                                    \
    }                                                                          \
    __syncthreads();                                                           \
    if (t < 128) {                                                             \
      float sn = pn_s[0] + pn_s[1];                                            \
      float f = sn / ((1.f + sn) * (sqrtf(sn) + 1e-8f));                       \
      float v = f * sv;                                                        \
      if (t < 64) vB[t] = v;                                                   \
      if (LASTF) caps[((size_t)g * O_ + o) * OUTD + t] = v;                    \
    }                                                                          \
    __syncthreads();                                                           \
    if (!(LASTF)) {                                                            \
      if (t < 128) {  /* wvacc update, 2-way s-split (validated) */            \
        const int k = t >> 1, half = t & 1;                                    \
        const float* Wr = Ws + ((size_t)o * 64 + k) * 64 + half * 32;          \
        float acc = 0.f;                                                       \
        _Pragma("unroll")                                                      \
        for (int ss = 0; ss < 32; ss += 4) {                                   \
          float4 wq = *(const float4*)(Wr + ss);                               \
          float4 vq = *(const float4*)&vB[half * 32 + ss];                     \
          acc += wq.x*vq.x + wq.y*vq.y + wq.z*vq.z + wq.w*vq.w;                \
        }                                                                      \
        acc += __shfl_xor(acc, 1);                                             \
        if (half == 0)                                                         \
          wv_acc_s[k] = ((FIRSTF) ? 0.f : wv_acc_s[k]) + acc;                  \
      }                                                                        \
      __syncthreads();                                                         \
      if (t < 16) {   /* pack bf16 x4 -> u64 coherent store (validated) */     \
        const int k = t * 4;                                                   \
        u64_t v4 =  (u64_t)(unsigned short)f2bf(wv_acc_s[k + 0])               \
                 | ((u64_t)(unsigned short)f2bf(wv_acc_s[k + 1]) << 16)        \
                 | ((u64_t)(unsigned short)f2bf(wv_acc_s[k + 2]) << 32)        \
                 | ((u64_t)(unsigned short)f2bf(wv_acc_s[k + 3]) << 48);       \
        __hip_atomic_store(                                                    \
            (u64_t*)&wvacc_bf[(size_t)g * 1024 + o * 64 + k],                  \
            v4, __ATOMIC_RELAXED, __HIP_MEMORY_SCOPE_AGENT);                   \
      }                                                                        \
    } else {                                                                   \
      if (t < 24) {                                                            \
        const int idx = o * VC + 2 * t;                                        \
        const float* rp = routed_part + (size_t)g * CPG * 768 + idx;           \
        float s0 = 0.f, s1 = 0.f;                                              \
        _Pragma("unroll")                                                      \
        for (int ch = 0; ch < CPG; ++ch) {                                     \
          float a, bb; ld8f(&rp[ch * 768], a, bb);                             \
          s0 += a; s1 += bb;                                                   \
        }                                                                      \
        vecs[(size_t)g * 768 + idx] = s0;                                      \
        vecs[(size_t)g * 768 + idx + 1] = s1;                                  \
      }                                                                        \
    }                                                                          \
  }

  // ================= routing iterations =================
  B_ROLE(1, 0)                 // it0 B: v0 from colsums, wvacc '='
  graph_barrier(cnt, 32);
  A_ROLE(0)                    // it1 A
  graph_barrier(cnt, 48);
  B_ROLE(0, 0)                 // it1 B: wvacc '+='
  graph_barrier(cnt, 64);
  A_ROLE(1)                    // it2 A: + cp + routed partials
  graph_barrier(cnt, 80);
  B_ROLE(0, 1)                 // it2 B: caps + vecs

#undef A_ROLE
#undef B_ROLE
}

// ---------------------------------------------------------------------------
extern "C" void kernel_launch(void* const* d_in, const int* in_sizes, int n_in,
                              void* d_out, int out_size, void* d_ws, size_t ws_size,
                              hipStream_t stream)
{
  const float* x    = (const float*)d_in[0];
  const float* xv   = (const float*)d_in[1];
  const float* Ws   = (const float*)d_in[2];
  const float* Wv   = (const float*)d_in[3];
  const float* bias = (const float*)d_in[4];

  float* out  = (float*)d_out;
  float* caps = out;                           // (32,16,128)
  float* vecs = out + (size_t)G_ * O_ * OUTD;  // (32,16,16,3)

  // ws layout: bar (2048 u32) | ysum_part 65536 f | y_part 1048576 f
  //            | routed 393216 f | wvacc_bf 32768 bf16
  float* ws          = (float*)d_ws;
  unsigned* bar      = (unsigned*)ws;
  float* ysum_part   = ws + 4096;
  float* y_part      = ysum_part + (size_t)G_ * CPG * 128;
  float* routed_part = y_part + (size_t)G_ * CPG * 2048;
  short* wvacc_bf    = (short*)(routed_part + (size_t)G_ * CPG * 768);

  hipMemsetAsync((void*)bar, 0, (size_t)G_ * 64 * sizeof(unsigned), stream);
  caps_mega6<<<dim3(G_ * CPG), dim3(512), 0, stream>>>(
      x, xv, Ws, Wv, bias, wvacc_bf, y_part, routed_part, ysum_part,
      caps, vecs, bar);
}